// Round 10
// baseline (204.268 us; speedup 1.0000x reference)
//
#include <hip/hip_runtime.h>
#include <hip/hip_bf16.h>

// ZDecoder: qs[b,c,o] = MLP(concat(V(c), phi(b)))
// R9 post-mortem: NT made traffic optimal (FETCH 2MB, WRITE 134MB) but time
// unchanged vs R7 -> not traffic-bound. Measured rate == 4 blocks/CU store
// drain (3.0 TB/s): limiter is per-CU parallelism + serial step chain.
// R10: (a) grid 2048, block = 1 batch x 512 combos -> r3 block-uniform,
// afp[16] in regs, NO A01 table (LDS 8.4 KB); (b) NO store staging -- direct
// sector-complete NT dwordx4 stores from MFMA regs (chain loses ds_write +
// lgkmcnt + drain reads); (c) launch_bounds(256,8) -> 8 blocks/CU, 32 waves/CU.

typedef __attribute__((ext_vector_type(8))) short bf16x8;
typedef __attribute__((ext_vector_type(4))) short bf16x4;
typedef __attribute__((ext_vector_type(4))) float f32x4;

#define MFMA_K32(a, b, c) __builtin_amdgcn_mfma_f32_16x16x32_bf16(a, b, c, 0, 0, 0)

#if defined(__has_builtin)
#if __has_builtin(__builtin_amdgcn_mfma_f32_16x16x16bf16_1k)
#define MFMA_K16(a, b, c) __builtin_amdgcn_mfma_f32_16x16x16bf16_1k(a, b, c, 0, 0, 0)
#elif __has_builtin(__builtin_amdgcn_mfma_f32_16x16x16_bf16)
#define MFMA_K16(a, b, c) __builtin_amdgcn_mfma_f32_16x16x16_bf16(a, b, c, 0, 0, 0)
#endif
#endif
#ifndef MFMA_K16
__device__ __forceinline__ f32x4 mfma_k16_asm(bf16x4 a, bf16x4 b, f32x4 c) {
    f32x4 d;
    asm("v_mfma_f32_16x16x16_bf16 %0, %1, %2, %3" : "=v"(d) : "v"(a), "v"(b), "v"(c));
    return d;
}
#define MFMA_K16(a, b, c) mfma_k16_asm(a, b, c)
#endif

__device__ __forceinline__ short f2bf(float x) {
    union { __hip_bfloat16 b; short s; } u;
    u.b = __float2bfloat16(x);
    return u.s;
}

__device__ __forceinline__ float4 ldg4(const float* p) {
    return *reinterpret_cast<const float4*>(p);
}

__global__ __launch_bounds__(256, 8)
void zdec_kernel(const float* __restrict__ phi, const float* __restrict__ rp,
                 const float* __restrict__ w1, const float* __restrict__ b1,
                 const float* __restrict__ w2, const float* __restrict__ b2,
                 const float* __restrict__ w3, const float* __restrict__ b3,
                 float* __restrict__ out)
{
    // 8.4 KiB: Bt[2048] | Pt[64]
    __shared__ float smem[2112];
    float* const Bt = smem;          // [4 lv][8 rg][64 h]
    float* const Pt = smem + 2048;   // [64 h] this block's batch

    const int t    = threadIdx.x;
    const int b    = blockIdx.x >> 3;  // batch 0..255
    const int cbi8 = blockIdx.x & 7;   // combo octant: combos [cbi8*512, +512)

    // ---------------- setup: B table ----------------
    {
        const int l = t >> 6, h = t & 63;
        float ws[16];
#pragma unroll
        for (int z4 = 0; z4 < 4; ++z4) {
            const float4 v = ldg4(w1 + h * 128 + l * 16 + z4 * 4);
            ws[z4*4+0] = v.x; ws[z4*4+1] = v.y; ws[z4*4+2] = v.z; ws[z4*4+3] = v.w;
        }
#pragma unroll
        for (int r = 0; r < 8; ++r) {
            float acc = 0.f;
#pragma unroll
            for (int z4 = 0; z4 < 4; ++z4) {
                const float4 v = ldg4(rp + (l * 8 + r) * 16 + z4 * 4);
                acc += ws[z4*4+0]*v.x + ws[z4*4+1]*v.y + ws[z4*4+2]*v.z + ws[z4*4+3]*v.w;
            }
            Bt[(l * 8 + r) * 64 + h] = acc;
        }
    }
    // ---------------- setup: P row ----------------
    if (t < 64) {
        const int h = t;
        float acc = b1[h];
#pragma unroll
        for (int p4 = 0; p4 < 16; ++p4) {
            const float4 wv = ldg4(w1 + h * 128 + 64 + p4 * 4);
            const float4 pv = ldg4(phi + b * 64 + p4 * 4);
            acc += wv.x * pv.x + wv.y * pv.y + wv.z * pv.z + wv.w * pv.w;
        }
        Pt[h] = acc;
    }
    __syncthreads();

    // ---------------- main: 8 steps x 64 combos (contiguous ascending) -------
    const int lane = t & 63;
    const int wid  = t >> 6;
    const int q = lane >> 4;
    const int s = lane & 15;
    const int row = (wid << 4) + s;   // lane's combo-low (bits 0..5 of c)

    // w2 as layer-2 A-operand: A[m=g=nt*16+s][k=h=kt*32+q*8+j]
    bf16x8 w2f[4][2];
#pragma unroll
    for (int nt = 0; nt < 4; ++nt)
#pragma unroll
        for (int kt = 0; kt < 2; ++kt) {
            const float* src = w2 + (nt * 16 + s) * 64 + kt * 32 + q * 8;
            const float4 v0 = ldg4(src), v1 = ldg4(src + 4);
            bf16x8 f;
            f[0]=f2bf(v0.x); f[1]=f2bf(v0.y); f[2]=f2bf(v0.z); f[3]=f2bf(v0.w);
            f[4]=f2bf(v1.x); f[5]=f2bf(v1.y); f[6]=f2bf(v1.z); f[7]=f2bf(v1.w);
            w2f[nt][kt] = f;
        }
    // w3 as layer-3 K=16 A-operand: A[m=o=nt3*16+s][k=g=nt*16+q*4+j]
    bf16x4 w3f[2][4];
#pragma unroll
    for (int nt3 = 0; nt3 < 2; ++nt3)
#pragma unroll
        for (int nt = 0; nt < 4; ++nt) {
            const float4 v = ldg4(w3 + (nt3 * 16 + s) * 64 + nt * 16 + q * 4);
            bf16x4 f;
            f[0]=f2bf(v.x); f[1]=f2bf(v.y); f[2]=f2bf(v.z); f[3]=f2bf(v.w);
            w3f[nt3][nt] = f;
        }
    f32x4 b2i[4];
#pragma unroll
    for (int nt = 0; nt < 4; ++nt) {
        const float4 v = ldg4(b2 + nt * 16 + q * 4);
        b2i[nt] = f32x4{v.x, v.y, v.z, v.w};
    }
    f32x4 b3i[2];
#pragma unroll
    for (int nt3 = 0; nt3 < 2; ++nt3) {
        const float4 v = ldg4(b3 + nt3 * 16 + q * 4);
        b3i[nt3] = f32x4{v.x, v.y, v.z, v.w};
    }

    // afp = Bt0[row&7] + Bt1[(row>>3)&7] + P + Bt3[cbi8]  (r3 uniform per block)
    float afp[16];
    {
        const float* a0 = Bt + (row & 7) * 64;
        const float* a1 = Bt + (8 + ((row >> 3) & 7)) * 64;
        const float* a3 = Bt + (24 + cbi8) * 64;
#pragma unroll
        for (int c4 = 0; c4 < 4; ++c4) {
            const int hc = (c4 >> 1) * 32 + q * 8 + (c4 & 1) * 4;
            const f32x4 v0 = *reinterpret_cast<const f32x4*>(a0 + hc);
            const f32x4 v1 = *reinterpret_cast<const f32x4*>(a1 + hc);
            const f32x4 vp = *reinterpret_cast<const f32x4*>(Pt + hc);
            const f32x4 v3 = *reinterpret_cast<const f32x4*>(a3 + hc);
#pragma unroll
            for (int j = 0; j < 4; ++j)
                afp[c4*4+j] = v0[j] + v1[j] + vp[j] + v3[j];
        }
    }

    // wave's region: combos [cbi8*512 + mt*64 + wid*16, +16), 2 KiB per step
    float* const gwbase = out + ((size_t)b * 4096 + (cbi8 << 9) + (wid << 4)) * 32;

#pragma unroll
    for (int mt = 0; mt < 8; ++mt) {
        // h1 = relu(afp + Bt2[mt]) -> bf16 fragment [n=combo][k=h]
        bf16x8 h1f0, h1f1;
        {
            const float* bt2 = Bt + (16 + mt) * 64;
            float tmp[16];
#pragma unroll
            for (int c4 = 0; c4 < 4; ++c4) {
                const int hc = (c4 >> 1) * 32 + q * 8 + (c4 & 1) * 4;
                const f32x4 v2 = *reinterpret_cast<const f32x4*>(bt2 + hc);
#pragma unroll
                for (int j = 0; j < 4; ++j)
                    tmp[c4*4+j] = fmaxf(afp[c4*4+j] + v2[j], 0.f);
            }
#pragma unroll
            for (int j = 0; j < 8; ++j) h1f0[j] = f2bf(tmp[j]);
#pragma unroll
            for (int j = 0; j < 8; ++j) h1f1[j] = f2bf(tmp[8 + j]);
        }
        // layer 2: D2[m=g][n=combo]
        f32x4 a2[4];
#pragma unroll
        for (int nt = 0; nt < 4; ++nt) {
            f32x4 acc = b2i[nt];
            acc = MFMA_K32(w2f[nt][0], h1f0, acc);
            acc = MFMA_K32(w2f[nt][1], h1f1, acc);
            a2[nt] = acc;
        }
        // relu + cvt: D2 regs ARE the K=16 B-fragment [n=s][k=g=q*4+r]
        bf16x4 h2f[4];
#pragma unroll
        for (int nt = 0; nt < 4; ++nt) {
            bf16x4 f;
#pragma unroll
            for (int r = 0; r < 4; ++r) f[r] = f2bf(fmaxf(a2[nt][r], 0.f));
            h2f[nt] = f;
        }
        // layer 3 + direct NT stores: lane writes 16B at combo=s, o=nt3*16+q*4;
        // quad (s fixed, q=0..3) covers each 64B sector fully -> no RMW (R5/R9).
        float* gb = gwbase + mt * 2048;
#pragma unroll
        for (int nt3 = 0; nt3 < 2; ++nt3) {
            f32x4 acc = b3i[nt3];
#pragma unroll
            for (int nt = 0; nt < 4; ++nt)
                acc = MFMA_K16(w3f[nt3][nt], h2f[nt], acc);
            __builtin_nontemporal_store(acc,
                reinterpret_cast<f32x4*>(gb + s * 32 + nt3 * 16 + q * 4));
        }
    }
}

extern "C" void kernel_launch(void* const* d_in, const int* in_sizes, int n_in,
                              void* d_out, int out_size, void* d_ws, size_t ws_size,
                              hipStream_t stream) {
    const float* phi = (const float*)d_in[0];
    const float* rp  = (const float*)d_in[1];
    const float* w1  = (const float*)d_in[2];
    const float* b1  = (const float*)d_in[3];
    const float* w2  = (const float*)d_in[4];
    const float* b2  = (const float*)d_in[5];
    const float* w3  = (const float*)d_in[6];
    const float* b3  = (const float*)d_in[7];
    (void)in_sizes; (void)n_in; (void)out_size; (void)d_ws; (void)ws_size;

    zdec_kernel<<<dim3(2048), dim3(256), 0, stream>>>(
        phi, rp, w1, b1, w2, b2, w3, b3, (float*)d_out);
}

// Round 11
// 72.878 us; speedup vs baseline: 2.8029x; 2.8029x over previous
//
#include <hip/hip_runtime.h>
#include <hip/hip_bf16.h>

// ZDecoder: qs[b,c,o] = MLP(concat(V(c), phi(b)))
// R10 post-mortem: (256,8) -> 64-reg unified budget -> massive spill (VGPR=32,
// 680 MB scratch traffic). Resident state ~88 VGPR caps us at 4 waves/SIMD.
// R11 = R10 with launch_bounds(256,4): direct sector-complete NT stores, NO
// main-loop LDS barriers, 8 independent steps/wave -> tests whether R9's 3.1
// TB/s was staging-barrier serialization (predict 28-36us) or an NT-path cap
// (predict ~43us -> roofline).

typedef __attribute__((ext_vector_type(8))) short bf16x8;
typedef __attribute__((ext_vector_type(4))) short bf16x4;
typedef __attribute__((ext_vector_type(4))) float f32x4;

#define MFMA_K32(a, b, c) __builtin_amdgcn_mfma_f32_16x16x32_bf16(a, b, c, 0, 0, 0)

#if defined(__has_builtin)
#if __has_builtin(__builtin_amdgcn_mfma_f32_16x16x16bf16_1k)
#define MFMA_K16(a, b, c) __builtin_amdgcn_mfma_f32_16x16x16bf16_1k(a, b, c, 0, 0, 0)
#elif __has_builtin(__builtin_amdgcn_mfma_f32_16x16x16_bf16)
#define MFMA_K16(a, b, c) __builtin_amdgcn_mfma_f32_16x16x16_bf16(a, b, c, 0, 0, 0)
#endif
#endif
#ifndef MFMA_K16
__device__ __forceinline__ f32x4 mfma_k16_asm(bf16x4 a, bf16x4 b, f32x4 c) {
    f32x4 d;
    asm("v_mfma_f32_16x16x16_bf16 %0, %1, %2, %3" : "=v"(d) : "v"(a), "v"(b), "v"(c));
    return d;
}
#define MFMA_K16(a, b, c) mfma_k16_asm(a, b, c)
#endif

__device__ __forceinline__ short f2bf(float x) {
    union { __hip_bfloat16 b; short s; } u;
    u.b = __float2bfloat16(x);
    return u.s;
}

__device__ __forceinline__ float4 ldg4(const float* p) {
    return *reinterpret_cast<const float4*>(p);
}

__global__ __launch_bounds__(256, 4)
void zdec_kernel(const float* __restrict__ phi, const float* __restrict__ rp,
                 const float* __restrict__ w1, const float* __restrict__ b1,
                 const float* __restrict__ w2, const float* __restrict__ b2,
                 const float* __restrict__ w3, const float* __restrict__ b3,
                 float* __restrict__ out)
{
    // 8.4 KiB: Bt[2048] | Pt[64]
    __shared__ float smem[2112];
    float* const Bt = smem;          // [4 lv][8 rg][64 h]
    float* const Pt = smem + 2048;   // [64 h] this block's batch

    const int t    = threadIdx.x;
    const int b    = blockIdx.x >> 3;  // batch 0..255
    const int cbi8 = blockIdx.x & 7;   // combo octant: combos [cbi8*512, +512)

    // ---------------- setup: B table ----------------
    {
        const int l = t >> 6, h = t & 63;
        float ws[16];
#pragma unroll
        for (int z4 = 0; z4 < 4; ++z4) {
            const float4 v = ldg4(w1 + h * 128 + l * 16 + z4 * 4);
            ws[z4*4+0] = v.x; ws[z4*4+1] = v.y; ws[z4*4+2] = v.z; ws[z4*4+3] = v.w;
        }
#pragma unroll
        for (int r = 0; r < 8; ++r) {
            float acc = 0.f;
#pragma unroll
            for (int z4 = 0; z4 < 4; ++z4) {
                const float4 v = ldg4(rp + (l * 8 + r) * 16 + z4 * 4);
                acc += ws[z4*4+0]*v.x + ws[z4*4+1]*v.y + ws[z4*4+2]*v.z + ws[z4*4+3]*v.w;
            }
            Bt[(l * 8 + r) * 64 + h] = acc;
        }
    }
    // ---------------- setup: P row ----------------
    if (t < 64) {
        const int h = t;
        float acc = b1[h];
#pragma unroll
        for (int p4 = 0; p4 < 16; ++p4) {
            const float4 wv = ldg4(w1 + h * 128 + 64 + p4 * 4);
            const float4 pv = ldg4(phi + b * 64 + p4 * 4);
            acc += wv.x * pv.x + wv.y * pv.y + wv.z * pv.z + wv.w * pv.w;
        }
        Pt[h] = acc;
    }
    __syncthreads();

    // ---------------- main: 8 independent steps x 64 combos ----------------
    const int lane = t & 63;
    const int wid  = t >> 6;
    const int q = lane >> 4;
    const int s = lane & 15;
    const int row = (wid << 4) + s;   // lane's combo-low (bits 0..5 of c)

    // w2 as layer-2 A-operand: A[m=g=nt*16+s][k=h=kt*32+q*8+j]
    bf16x8 w2f[4][2];
#pragma unroll
    for (int nt = 0; nt < 4; ++nt)
#pragma unroll
        for (int kt = 0; kt < 2; ++kt) {
            const float* src = w2 + (nt * 16 + s) * 64 + kt * 32 + q * 8;
            const float4 v0 = ldg4(src), v1 = ldg4(src + 4);
            bf16x8 f;
            f[0]=f2bf(v0.x); f[1]=f2bf(v0.y); f[2]=f2bf(v0.z); f[3]=f2bf(v0.w);
            f[4]=f2bf(v1.x); f[5]=f2bf(v1.y); f[6]=f2bf(v1.z); f[7]=f2bf(v1.w);
            w2f[nt][kt] = f;
        }
    // w3 as layer-3 K=16 A-operand: A[m=o=nt3*16+s][k=g=nt*16+q*4+j]
    bf16x4 w3f[2][4];
#pragma unroll
    for (int nt3 = 0; nt3 < 2; ++nt3)
#pragma unroll
        for (int nt = 0; nt < 4; ++nt) {
            const float4 v = ldg4(w3 + (nt3 * 16 + s) * 64 + nt * 16 + q * 4);
            bf16x4 f;
            f[0]=f2bf(v.x); f[1]=f2bf(v.y); f[2]=f2bf(v.z); f[3]=f2bf(v.w);
            w3f[nt3][nt] = f;
        }
    f32x4 b2i[4];
#pragma unroll
    for (int nt = 0; nt < 4; ++nt) {
        const float4 v = ldg4(b2 + nt * 16 + q * 4);
        b2i[nt] = f32x4{v.x, v.y, v.z, v.w};
    }
    f32x4 b3i[2];
#pragma unroll
    for (int nt3 = 0; nt3 < 2; ++nt3) {
        const float4 v = ldg4(b3 + nt3 * 16 + q * 4);
        b3i[nt3] = f32x4{v.x, v.y, v.z, v.w};
    }

    // afp = Bt0[row&7] + Bt1[(row>>3)&7] + P + Bt3[cbi8]  (r3 uniform per block)
    float afp[16];
    {
        const float* a0 = Bt + (row & 7) * 64;
        const float* a1 = Bt + (8 + ((row >> 3) & 7)) * 64;
        const float* a3 = Bt + (24 + cbi8) * 64;
#pragma unroll
        for (int c4 = 0; c4 < 4; ++c4) {
            const int hc = (c4 >> 1) * 32 + q * 8 + (c4 & 1) * 4;
            const f32x4 v0 = *reinterpret_cast<const f32x4*>(a0 + hc);
            const f32x4 v1 = *reinterpret_cast<const f32x4*>(a1 + hc);
            const f32x4 vp = *reinterpret_cast<const f32x4*>(Pt + hc);
            const f32x4 v3 = *reinterpret_cast<const f32x4*>(a3 + hc);
#pragma unroll
            for (int j = 0; j < 4; ++j)
                afp[c4*4+j] = v0[j] + v1[j] + vp[j] + v3[j];
        }
    }

    // wave's region: combos [cbi8*512 + mt*64 + wid*16, +16), 2 KiB per step
    float* const gwbase = out + ((size_t)b * 4096 + (cbi8 << 9) + (wid << 4)) * 32;

#pragma unroll
    for (int mt = 0; mt < 8; ++mt) {
        // h1 = relu(afp + Bt2[mt]) -> bf16 fragment [n=combo][k=h]
        bf16x8 h1f0, h1f1;
        {
            const float* bt2 = Bt + (16 + mt) * 64;
            float tmp[16];
#pragma unroll
            for (int c4 = 0; c4 < 4; ++c4) {
                const int hc = (c4 >> 1) * 32 + q * 8 + (c4 & 1) * 4;
                const f32x4 v2 = *reinterpret_cast<const f32x4*>(bt2 + hc);
#pragma unroll
                for (int j = 0; j < 4; ++j)
                    tmp[c4*4+j] = fmaxf(afp[c4*4+j] + v2[j], 0.f);
            }
#pragma unroll
            for (int j = 0; j < 8; ++j) h1f0[j] = f2bf(tmp[j]);
#pragma unroll
            for (int j = 0; j < 8; ++j) h1f1[j] = f2bf(tmp[8 + j]);
        }
        // layer 2: D2[m=g][n=combo]
        f32x4 a2[4];
#pragma unroll
        for (int nt = 0; nt < 4; ++nt) {
            f32x4 acc = b2i[nt];
            acc = MFMA_K32(w2f[nt][0], h1f0, acc);
            acc = MFMA_K32(w2f[nt][1], h1f1, acc);
            a2[nt] = acc;
        }
        // relu + cvt: D2 regs ARE the K=16 B-fragment [n=s][k=g=q*4+r]
        bf16x4 h2f[4];
#pragma unroll
        for (int nt = 0; nt < 4; ++nt) {
            bf16x4 f;
#pragma unroll
            for (int r = 0; r < 4; ++r) f[r] = f2bf(fmaxf(a2[nt][r], 0.f));
            h2f[nt] = f;
        }
        // layer 3 + direct NT stores: lane writes 16B at combo=s, o=nt3*16+q*4;
        // quad (s fixed, q=0..3) covers each 64B sector fully -> no RMW (R5/R9).
        float* gb = gwbase + mt * 2048;
#pragma unroll
        for (int nt3 = 0; nt3 < 2; ++nt3) {
            f32x4 acc = b3i[nt3];
#pragma unroll
            for (int nt = 0; nt < 4; ++nt)
                acc = MFMA_K16(w3f[nt3][nt], h2f[nt], acc);
            __builtin_nontemporal_store(acc,
                reinterpret_cast<f32x4*>(gb + s * 32 + nt3 * 16 + q * 4));
        }
    }
}

extern "C" void kernel_launch(void* const* d_in, const int* in_sizes, int n_in,
                              void* d_out, int out_size, void* d_ws, size_t ws_size,
                              hipStream_t stream) {
    const float* phi = (const float*)d_in[0];
    const float* rp  = (const float*)d_in[1];
    const float* w1  = (const float*)d_in[2];
    const float* b1  = (const float*)d_in[3];
    const float* w2  = (const float*)d_in[4];
    const float* b2  = (const float*)d_in[5];
    const float* w3  = (const float*)d_in[6];
    const float* b3  = (const float*)d_in[7];
    (void)in_sizes; (void)n_in; (void)out_size; (void)d_ws; (void)ws_size;

    zdec_kernel<<<dim3(2048), dim3(256), 0, stream>>>(
        phi, rp, w1, b1, w2, b2, w3, b3, (float*)d_out);
}